// Round 7
// baseline (28.683 us; speedup 1.0000x reference)
//
#include <hip/hip_runtime.h>

typedef __attribute__((ext_vector_type(4))) float f32x4;

constexpr int Bdim = 8192;   // rows of x
constexpr int Cdim = 4096;   // rows of W (= output cols)
constexpr int Ddim = 256;    // K

// 15*exp(-t) == +0.0f in f32 (incl. denormal range) for t >= ~106.7; margin -> 112.
constexpr float ZERO_THRESH = 112.0f;

// ---------------------------------------------------------------------------
// Kernel 1: norms pass. Blocks 0..2047: xsq[row] = ||x_row||^2 (one wave/row,
// 4 rows/block). Blocks 2048..3071: pmax[b] = max of 4 ||W_row||^2.
// Reads 12.6 MB, writes 36 KB.
// ---------------------------------------------------------------------------
__global__ __launch_bounds__(256) void norms_kernel(const float* __restrict__ x,
                                                    const float* __restrict__ W,
                                                    float* __restrict__ xsq,
                                                    float* __restrict__ pmax) {
  __shared__ float sm[4];
  int tid  = threadIdx.x;
  int lane = tid & 63;
  int wid  = tid >> 6;
  int b    = blockIdx.x;

  if (b < Bdim / 4) {
    int row = b * 4 + wid;
    f32x4 v = *(const f32x4*)(x + (size_t)row * Ddim + lane * 4);
    float s = v[0]*v[0] + v[1]*v[1] + v[2]*v[2] + v[3]*v[3];
    #pragma unroll
    for (int off = 32; off > 0; off >>= 1) s += __shfl_xor(s, off, 64);
    if (lane == 0) xsq[row] = s;
  } else {
    int row = (b - Bdim / 4) * 4 + wid;
    f32x4 v = *(const f32x4*)(W + (size_t)row * Ddim + lane * 4);
    float s = v[0]*v[0] + v[1]*v[1] + v[2]*v[2] + v[3]*v[3];
    #pragma unroll
    for (int off = 32; off > 0; off >>= 1) s += __shfl_xor(s, off, 64);
    if (lane == 0) sm[wid] = s;
    __syncthreads();
    if (tid == 0) pmax[b - Bdim / 4] = fmaxf(fmaxf(sm[0], sm[1]), fmaxf(sm[2], sm[3]));
  }
}

// ---------------------------------------------------------------------------
// Kernel 2: persistent fill. 512 blocks x 16 output rows (256 KB contiguous
// each). Per block: ONE pmax[1024] scan -> global max||W||; then 4 slabs of
// 4 rows, each screened via Cauchy-Schwarz (||x_b - w_c||^2 >= (||x_b|| -
// max||W||)^2 > 112 -> slab outputs are exactly +0.0f in f32) and filled
// with a tight f32x4 store loop (regular stores: L2 write-combine is the
// fast path on gfx950; nontemporal stores measured -25% in R5). Slow path
// (block-uniform, not taken for the bench input): exact f32 metric.
// ---------------------------------------------------------------------------
__global__ __launch_bounds__(256) void rbf_fill(const float* __restrict__ x,
                                                const float* __restrict__ W,
                                                const float* __restrict__ xsq,
                                                const float* __restrict__ pmax,
                                                float* __restrict__ out) {
  __shared__ float wm4[4];
  __shared__ float xl[4][Ddim];   // slow path only (4 KB)

  int tid  = threadIdx.x;
  int lane = tid & 63;
  int wid  = tid >> 6;

  // once per block: global max ||W||^2 from the 1024 partial maxes
  float wmx = fmaxf(fmaxf(pmax[tid], pmax[tid + 256]),
                    fmaxf(pmax[tid + 512], pmax[tid + 768]));
  #pragma unroll
  for (int off = 32; off > 0; off >>= 1) wmx = fmaxf(wmx, __shfl_xor(wmx, off, 64));
  if (lane == 0) wm4[wid] = wmx;
  __syncthreads();
  float wnorm = sqrtf(fmaxf(fmaxf(wm4[0], wm4[1]), fmaxf(wm4[2], wm4[3])));

  int row_base = blockIdx.x * 16;

  #pragma unroll 1
  for (int s = 0; s < 4; ++s) {
    int row0 = row_base + s * 4;

    // slab screen: min ||x||^2 over the 4 rows (2 shuffles; L2-hot loads)
    float xn = xsq[row0 + (tid & 3)];
    xn = fminf(xn, __shfl_xor(xn, 1, 64));
    xn = fminf(xn, __shfl_xor(xn, 2, 64));
    float gap = sqrtf(xn) - wnorm;

    if (gap > 0.0f && gap * gap > ZERO_THRESH) {
      // fast path: 64 KB contiguous zero fill
      f32x4 z = {0.0f, 0.0f, 0.0f, 0.0f};
      float* base = out + (size_t)row0 * Cdim + tid * 4;
      #pragma unroll
      for (int p = 0; p < 16; ++p)
        *(f32x4*)(base + (size_t)p * 1024) = z;
    } else {
      // slow path: exact f32 metric for the slab (block-uniform branch)
      f32x4 v = *(const f32x4*)(x + (size_t)row0 * Ddim + tid * 4);
      *(f32x4*)&xl[wid][lane * 4] = v;
      __syncthreads();
      for (int ch = 0; ch < Cdim / 256; ++ch) {
        int col = ch * 256 + tid;
        const float* wrow = W + (size_t)col * Ddim;
        float m0 = 0.f, m1 = 0.f, m2 = 0.f, m3 = 0.f;
        for (int d = 0; d < Ddim; d += 4) {
          f32x4 wv = *(const f32x4*)(wrow + d);
          #pragma unroll
          for (int e = 0; e < 4; ++e) {
            float w  = wv[e];
            float d0 = w - xl[0][d + e]; m0 += d0 * d0;
            float d1 = w - xl[1][d + e]; m1 += d1 * d1;
            float d2 = w - xl[2][d + e]; m2 += d2 * d2;
            float d3 = w - xl[3][d + e]; m3 += d3 * d3;
          }
        }
        out[(size_t)(row0 + 0) * Cdim + col] = 15.0f * expf(-m0);
        out[(size_t)(row0 + 1) * Cdim + col] = 15.0f * expf(-m1);
        out[(size_t)(row0 + 2) * Cdim + col] = 15.0f * expf(-m2);
        out[(size_t)(row0 + 3) * Cdim + col] = 15.0f * expf(-m3);
      }
      __syncthreads();   // xl reused by next slab iteration
    }
  }
}

extern "C" void kernel_launch(void* const* d_in, const int* in_sizes, int n_in,
                              void* d_out, int out_size, void* d_ws, size_t ws_size,
                              hipStream_t stream) {
  const float* x = (const float*)d_in[0];   // [8192, 256] f32
  const float* W = (const float*)d_in[1];   // [4096, 256] f32
  float* out     = (float*)d_out;           // [8192, 4096] f32
  float* xsq     = (float*)d_ws;            // 8192 f32
  float* pmax    = xsq + Bdim;              // 1024 f32 (total 36 KB scratch)

  // 1) all row norms: 2048 x-blocks + 1024 W-blocks
  norms_kernel<<<Bdim / 4 + Cdim / 4, 256, 0, stream>>>(x, W, xsq, pmax);

  // 2) persistent screened fill: 512 blocks x 16 rows
  rbf_fill<<<Bdim / 16, 256, 0, stream>>>(x, W, xsq, pmax, out);
}